// Round 9
// baseline (1132.208 us; speedup 1.0000x reference)
//
#include <hip/hip_runtime.h>
#include <hip/hip_bf16.h>
#include <stdint.h>

#define DD 1024   // hidden dim
#define BB 4      // batch
#define TT 2048   // seq len
#define VV 16000  // vocab
#define LCH 8     // chunk length
#define NR 1024   // BB*(TT/LCH) rows, r = c*4 + b
#define NPAD 16128
#define M1C ((size_t)DD * DD)

typedef __bf16 bf16_t;
typedef float f32x4_t __attribute__((ext_vector_type(4)));
typedef bf16_t bf16x8_t __attribute__((ext_vector_type(8)));
typedef bf16_t bf16x4_t __attribute__((ext_vector_type(4)));

#define KIND_SQ 0
#define KIND_ROUND 1
#define KIND_LEVEL 2
#define KIND_CARRY 3

__device__ __forceinline__ void gload16(const void* g, void* l) {
  __builtin_amdgcn_global_load_lds((const __attribute__((address_space(1))) void*)g,
                                   (__attribute__((address_space(3))) void*)l, 16, 0, 0);
}

// ---------------- fp32 -> bf16 convert (lm_w) ----------------
__global__ __launch_bounds__(256) void k_cvt(const float* __restrict__ src,
                                             bf16_t* __restrict__ dst, int n4) {
  int i = blockIdx.x * blockDim.x + threadIdx.x;
  int stride = gridDim.x * blockDim.x;
  for (; i < n4; i += stride) {
    float4 v = ((const float4*)src)[i];
    union { ushort4 u; bf16_t h[4]; } p;
    p.h[0] = (bf16_t)v.x; p.h[1] = (bf16_t)v.y;
    p.h[2] = (bf16_t)v.z; p.h[3] = (bf16_t)v.w;
    ((ushort4*)dst)[i] = p.u;
  }
}

// ------------- gather chunk-start embed rows -> LOC slab0 (2-plane bf16) -----
__global__ __launch_bounds__(256) void k_gather2(const float* __restrict__ embed,
                                                 const int* __restrict__ ids,
                                                 bf16_t* __restrict__ slab0) {
  int r = blockIdx.x;  // 0..1023
  int b = r & 3, c = r >> 2;
  int id = ids[b * TT + c * LCH];
  const float4* s = (const float4*)(embed + (size_t)id * DD);
  bf16_t* p0 = slab0 + (size_t)r * DD;
  bf16_t* p1 = p0 + M1C;
  for (int i = threadIdx.x; i < DD / 4; i += blockDim.x) {
    float4 v = s[i];
    union { ushort4 u; bf16_t h[4]; } a, bq;
    a.h[0] = (bf16_t)v.x; bq.h[0] = (bf16_t)(v.x - (float)a.h[0]);
    a.h[1] = (bf16_t)v.y; bq.h[1] = (bf16_t)(v.y - (float)a.h[1]);
    a.h[2] = (bf16_t)v.z; bq.h[2] = (bf16_t)(v.z - (float)a.h[2]);
    a.h[3] = (bf16_t)v.w; bq.h[3] = (bf16_t)(v.w - (float)a.h[3]);
    ((ushort4*)p0)[i] = a.u;
    ((ushort4*)p1)[i] = bq.u;
  }
}

// ---------------- chain job descriptors ----------------
struct JobC {
  const void* A; const void* B; void* C; const void* Cin;
  int kind; int dlt; int shift;
};
struct JobsC { JobC j[8]; };

// ---------------- SQ path: fp32 NN squaring GEMM, NS=3 split (round-5) -------
template <int NS>
__device__ __forceinline__ void swrite(char* base, int byteoff, float4 v) {
  float r0 = v.x, r1 = v.y, r2 = v.z, r3 = v.w;
#pragma unroll
  for (int p = 0; p < NS; ++p) {
    bf16x4_t h;
    h[0] = (bf16_t)r0; h[1] = (bf16_t)r1; h[2] = (bf16_t)r2; h[3] = (bf16_t)r3;
    *(bf16x4_t*)(base + p * 5120 + byteoff) = h;
    if (p + 1 < NS) {
      r0 -= (float)h[0]; r1 -= (float)h[1]; r2 -= (float)h[2]; r3 -= (float)h[3];
    }
  }
}

__device__ __forceinline__ void mbodySQ(bf16_t* __restrict__ SBb, const JobC& jb) {
  const float* A = (const float*)jb.A;
  const float* Bm = (const float*)jb.B;
  float* Cm = (float*)jb.C;
  const int tid = threadIdx.x, lane = tid & 63, wave = tid >> 6;
  const int i0 = blockIdx.y * 64, j0 = blockIdx.x * 64;
  const int wm = (wave >> 1) * 32, wn = (wave & 1) * 32;
  char* Ap = (char*)SBb;
  char* Bp = Ap + 3 * 5120;
  const int arow = tid >> 2;
  const int akb = (tid & 3) * 8;
  const int bj = tid & 63, bk4 = (tid >> 6) * 4;
  const int frow = lane & 15, fkb = (lane >> 4) * 16;
  f32x4_t acc[2][2] = {};

  const float* Aptr = A + (size_t)(i0 + arow) * DD + (tid & 3) * 4;
  const float* BptrNN = Bm + (size_t)bk4 * DD + j0 + bj;

  float4 a0 = *(const float4*)(Aptr);
  float4 a1 = *(const float4*)(Aptr + 16);
  float s0[4], s1[4];
#pragma unroll
  for (int s = 0; s < 4; ++s) s0[s] = BptrNN[(size_t)s * DD];
#pragma unroll
  for (int s = 0; s < 4; ++s) s1[s] = BptrNN[(size_t)(16 + s) * DD];

  for (int k0 = 0;;) {
    __syncthreads();
    swrite<3>(Ap, arow * 80 + akb, a0);
    swrite<3>(Ap, arow * 80 + akb + 32, a1);
    float4 t0; t0.x = s0[0]; t0.y = s0[1]; t0.z = s0[2]; t0.w = s0[3];
    float4 t1; t1.x = s1[0]; t1.y = s1[1]; t1.z = s1[2]; t1.w = s1[3];
    swrite<3>(Bp, bj * 80 + bk4 * 2, t0);
    swrite<3>(Bp, bj * 80 + bk4 * 2 + 32, t1);
    __syncthreads();
    int kn = k0 + 32;
    if (kn < DD) {
      a0 = *(const float4*)(Aptr + kn);
      a1 = *(const float4*)(Aptr + kn + 16);
#pragma unroll
      for (int s = 0; s < 4; ++s) s0[s] = BptrNN[(size_t)(kn + s) * DD];
#pragma unroll
      for (int s = 0; s < 4; ++s) s1[s] = BptrNN[(size_t)(kn + 16 + s) * DD];
    }
    bf16x8_t af[3][2], bfx[3][2];
#pragma unroll
    for (int p = 0; p < 3; ++p)
#pragma unroll
      for (int mf = 0; mf < 2; ++mf) {
        af[p][mf] = *(const bf16x8_t*)(Ap + p * 5120 + (wm + mf * 16 + frow) * 80 + fkb);
        bfx[p][mf] = *(const bf16x8_t*)(Bp + p * 5120 + (wn + mf * 16 + frow) * 80 + fkb);
      }
#pragma unroll
    for (int pa = 0; pa < 3; ++pa)
#pragma unroll
      for (int pb = 0; pb < 3; ++pb) {
        if (pa + pb < 3) {
#pragma unroll
          for (int mf = 0; mf < 2; ++mf)
#pragma unroll
            for (int nf = 0; nf < 2; ++nf)
              acc[mf][nf] = __builtin_amdgcn_mfma_f32_16x16x32_bf16(
                  af[pa][mf], bfx[pb][nf], acc[mf][nf], 0, 0, 0);
        }
      }
    k0 = kn;
    if (k0 >= DD) break;
  }

  const int ecol = lane & 15, er4 = (lane >> 4) * 4;
#pragma unroll
  for (int mf = 0; mf < 2; ++mf)
#pragma unroll
    for (int nf = 0; nf < 2; ++nf)
#pragma unroll
      for (int rg = 0; rg < 4; ++rg)
        Cm[(size_t)(i0 + wm + mf * 16 + er4 + rg) * DD + (j0 + wn + nf * 16 + ecol)] =
            acc[mf][nf][rg];
}

// ---------------- state path: no-LDS direct-frag split-bf16 GEMM -------------
// A = 2-plane bf16 (global per-lane frags); B = fp32, split in-register;
// 3-term MFMA (a0b0, a0b1, a1b0). Guards replace zero-row padding.
template <int MODE>  // 1=ROUND 2=LEVEL 3=CARRY
__device__ __forceinline__ void sbody(const JobC& jb,
                                      const float* __restrict__ embed,
                                      const int* __restrict__ ids,
                                      bf16_t* __restrict__ hid) {
  const bf16_t* Ab = (const bf16_t*)jb.A;  // plane stride M1C
  const float* Bf = (const float*)jb.B;
  const int tid = threadIdx.x, lane = tid & 63, wave = tid >> 6;
  const int i0 = blockIdx.y * 64, j0 = blockIdx.x * 64;
  const int wm = (wave >> 1) * 32, wn = (wave & 1) * 32;
  const int frow = lane & 15, fq = lane >> 4;
  const int shift = jb.shift;
  const int ar0 = i0 + wm + frow - shift;
  const int rb0 = j0 + wn + frow;
  f32x4_t acc[2][2] = {};

  for (int k0 = 0; k0 < DD; k0 += 32) {
    const int kk = k0 + fq * 8;
    bf16x8_t a0[2], a1[2];
#pragma unroll
    for (int mf = 0; mf < 2; ++mf) {
      int r = ar0 + mf * 16;
      if (r >= 0) {
        const bf16_t* ap = Ab + (size_t)r * DD + kk;
        a0[mf] = *(const bf16x8_t*)ap;
        a1[mf] = *(const bf16x8_t*)(ap + M1C);
      } else {
        a0[mf] = bf16x8_t{};
        a1[mf] = bf16x8_t{};
      }
    }
    bf16x8_t b0[2], b1[2];
#pragma unroll
    for (int nf = 0; nf < 2; ++nf) {
      const float* bp = Bf + (size_t)(rb0 + nf * 16) * DD + kk;
      float4 x = *(const float4*)bp;
      float4 y = *(const float4*)(bp + 4);
      float xs[8] = {x.x, x.y, x.z, x.w, y.x, y.y, y.z, y.w};
#pragma unroll
      for (int e = 0; e < 8; ++e) {
        bf16_t h = (bf16_t)xs[e];
        b0[nf][e] = h;
        b1[nf][e] = (bf16_t)(xs[e] - (float)h);
      }
    }
#pragma unroll
    for (int mf = 0; mf < 2; ++mf)
#pragma unroll
      for (int nf = 0; nf < 2; ++nf) {
        acc[mf][nf] = __builtin_amdgcn_mfma_f32_16x16x32_bf16(
            a0[mf], b0[nf], acc[mf][nf], 0, 0, 0);
        acc[mf][nf] = __builtin_amdgcn_mfma_f32_16x16x32_bf16(
            a0[mf], b1[nf], acc[mf][nf], 0, 0, 0);
        acc[mf][nf] = __builtin_amdgcn_mfma_f32_16x16x32_bf16(
            a1[mf], b0[nf], acc[mf][nf], 0, 0, 0);
      }
  }

  // epilogue; C/D: col = lane&15, row = (lane>>4)*4 + reg [m89-verified]
  const int ecol = lane & 15;
#pragma unroll
  for (int mf = 0; mf < 2; ++mf)
#pragma unroll
    for (int nf = 0; nf < 2; ++nf)
#pragma unroll
      for (int rg = 0; rg < 4; ++rg) {
        int ri = i0 + wm + mf * 16 + fq * 4 + rg;
        int cj = j0 + wn + nf * 16 + ecol;
        float v = acc[mf][nf][rg];
        size_t o = (size_t)ri * DD + cj;
        if (MODE == 1) {  // ROUND: + embed injection, out 2pl bf16
          int b = ri & 3, c = ri >> 2, t = c * LCH + jb.dlt;
          v += embed[(size_t)ids[b * TT + t] * DD + cj];
          bf16_t* Co = (bf16_t*)jb.C;
          bf16_t h0 = (bf16_t)v;
          Co[o] = h0; Co[o + M1C] = (bf16_t)(v - (float)h0);
        } else if (MODE == 2) {  // LEVEL: + Cin (2pl), out 2pl
          const bf16_t* Ci = (const bf16_t*)jb.Cin;
          v += (float)Ci[o] + (float)Ci[o + M1C];
          bf16_t* Co = (bf16_t*)jb.C;
          bf16_t h0 = (bf16_t)v;
          Co[o] = h0; Co[o + M1C] = (bf16_t)(v - (float)h0);
        } else {  // CARRY: + LOC (2pl) -> hidden bf16
          const bf16_t* Ci = (const bf16_t*)jb.Cin;
          v += (float)Ci[o] + (float)Ci[o + M1C];
          int b = ri & 3, c = ri >> 2, t = c * LCH + jb.dlt;
          hid[((size_t)b * TT + t) * DD + cj] = (bf16_t)v;
        }
      }
}

__global__ __launch_bounds__(256, 2) void k_chain(JobsC jobs,
                                                  const float* __restrict__ embed,
                                                  const int* __restrict__ ids,
                                                  bf16_t* __restrict__ hid) {
  __shared__ __align__(16) bf16_t SBb[6 * 2560];
  const JobC& jb = jobs.j[blockIdx.z];
  if (jb.kind == KIND_SQ) mbodySQ(SBb, jb);
  else if (jb.kind == KIND_ROUND) sbody<1>(jb, embed, ids, hid);
  else if (jb.kind == KIND_LEVEL) sbody<2>(jb, embed, ids, hid);
  else sbody<3>(jb, embed, ids, hid);
}

// ---------------- LM head: round-5 verified kernel (330 us) ------------------
#define NTK 32

__global__ __launch_bounds__(512, 2) void k_lmhead2(
    const bf16_t* __restrict__ Ah, const bf16_t* __restrict__ Bw,
    const float* __restrict__ bias, float* __restrict__ Cout) {
  __shared__ __align__(16) char LB[4 * 32768];
  const int tid = threadIdx.x, lane = tid & 63, wave = tid >> 6;
  const int wr = wave >> 2, wc = wave & 3;
  int orig = blockIdx.y * gridDim.x + blockIdx.x;
  int swz = (orig & 7) * 252 + (orig >> 3);
  int by = swz / 63, bx = swz % 63;
  const int m0 = by * 256, n0 = bx * 256;

  const int srow = tid >> 2;
  const int scb = (tid & 3) * 16;

  auto stage = [&](int t) {
    char* buf = LB + (size_t)(t & 3) * 32768;
#pragma unroll
    for (int p = 0; p < 2; ++p) {
      int row = p * 128 + srow;
      int sw = ((row >> 1) & 3) << 4;
      gload16((const char*)Ah + ((size_t)(m0 + row) * DD + t * 32) * 2 + (scb ^ sw),
              buf + p * 8192 + wave * 1024);
      gload16((const char*)Bw + ((size_t)(n0 + row) * DD + t * 32) * 2 + (scb ^ sw),
              buf + 16384 + p * 8192 + wave * 1024);
    }
  };

  const int frow = lane & 15;
  const int c4b = (lane >> 4) * 16;
  f32x4_t acc[8][4] = {};

  stage(0); stage(1); stage(2);
  asm volatile("s_waitcnt vmcnt(8)\ns_barrier" ::: "memory");

  for (int t = 0; t < NTK; ++t) {
    char* Abuf = LB + (size_t)(t & 3) * 32768;
    char* Bbuf = Abuf + 16384;
    if (t + 3 < NTK) stage(t + 3);
    bf16x8_t afr[4], bfr[4];
#pragma unroll
    for (int nf = 0; nf < 4; ++nf) {
      int r = wc * 64 + nf * 16 + frow;
      bfr[nf] = *(const bf16x8_t*)(Bbuf + r * 64 + (c4b ^ (((r >> 1) & 3) << 4)));
    }
#pragma unroll
    for (int mf = 0; mf < 4; ++mf) {
      int r = wr * 128 + mf * 16 + frow;
      afr[mf] = *(const bf16x8_t*)(Abuf + r * 64 + (c4b ^ (((r >> 1) & 3) << 4)));
    }
    __builtin_amdgcn_s_setprio(1);
#pragma unroll
    for (int mf = 0; mf < 4; ++mf)
#pragma unroll
      for (int nf = 0; nf < 4; ++nf)
        acc[mf][nf] = __builtin_amdgcn_mfma_f32_16x16x32_bf16(
            afr[mf], bfr[nf], acc[mf][nf], 0, 0, 0);
    __builtin_amdgcn_s_setprio(0);
#pragma unroll
    for (int mf = 0; mf < 4; ++mf) {
      int r = wr * 128 + 64 + mf * 16 + frow;
      afr[mf] = *(const bf16x8_t*)(Abuf + r * 64 + (c4b ^ (((r >> 1) & 3) << 4)));
    }
    __builtin_amdgcn_s_setprio(1);
#pragma unroll
    for (int mf = 0; mf < 4; ++mf)
#pragma unroll
      for (int nf = 0; nf < 4; ++nf)
        acc[4 + mf][nf] = __builtin_amdgcn_mfma_f32_16x16x32_bf16(
            afr[mf], bfr[nf], acc[4 + mf][nf], 0, 0, 0);
    __builtin_amdgcn_s_setprio(0);
    if (t < NTK - 3) {
      asm volatile("s_waitcnt vmcnt(8)\ns_barrier" ::: "memory");
    } else if (t == NTK - 3) {
      asm volatile("s_waitcnt vmcnt(4)\ns_barrier" ::: "memory");
    } else if (t == NTK - 2) {
      asm volatile("s_waitcnt vmcnt(0)\ns_barrier" ::: "memory");
    }
  }

  const int ecol = lane & 15, er4 = (lane >> 4) * 4;
#pragma unroll
  for (int mf = 0; mf < 8; ++mf) {
#pragma unroll
    for (int nf = 0; nf < 4; ++nf) {
      int gm = m0 + wr * 128 + mf * 16 + er4;
      int gn = n0 + wc * 64 + nf * 16 + ecol;
      if (gn < VV) {
        float bv = bias[gn];
#pragma unroll
        for (int rg = 0; rg < 4; ++rg)
          Cout[(size_t)(gm + rg) * VV + gn] = acc[mf][nf][rg] + bv;
      }
    }
  }
}

// ---------------- host orchestration ----------------
extern "C" void kernel_launch(void* const* d_in, const int* in_sizes, int n_in,
                              void* d_out, int out_size, void* d_ws, size_t ws_size,
                              hipStream_t stream) {
  (void)in_sizes; (void)n_in; (void)out_size; (void)ws_size;
  const int* ids = (const int*)d_in[0];
  const float* embed = (const float*)d_in[1];
  const float* w_state = (const float*)d_in[2];
  const float* lm_w = (const float*)d_in[3];
  const float* lm_b = (const float*)d_in[4];
  float* out = (float*)d_out;

  const size_t M1 = M1C;
  // layout (147.5 MB, under proven-safe 153.8):
  float* PW = (float*)d_ws;                    // 8*M1 fp32 : PW + n*M1 = W^{n+1}
  float* Qf = PW + 8 * M1;                     // 7*M1 fp32 : Q_j = W^{8*2^{j+1}}
  bf16_t* LOCb = (bf16_t*)(Qf + 7 * M1);       // 8 slabs * 2*M1 bf16 (2-plane)
  bf16_t* E0 = LOCb + 16 * M1;                 // 2*M1 bf16
  bf16_t* E1 = E0 + 2 * M1;                    // 2*M1 bf16
  bf16_t* HID = E1 + 2 * M1;                   // 8*M1 bf16
  bf16_t* LWB = HID + 8 * M1;                  // NPAD*DD bf16

  // setup
  k_cvt<<<2048, 256, 0, stream>>>(lm_w, LWB, VV * DD / 4);
  hipMemsetAsync(LWB + (size_t)VV * DD, 0,
                 (size_t)(NPAD - VV) * DD * sizeof(bf16_t), stream);
  hipMemcpyAsync(PW, w_state, M1 * sizeof(float), hipMemcpyDeviceToDevice, stream);
  k_gather2<<<NR, 256, 0, stream>>>(embed, ids, LOCb);

  auto SQ = [&](const float* A, const float* B, float* C) {
    return JobC{A, B, C, nullptr, KIND_SQ, 0, 0};
  };
  auto RD = [&](int d) {
    return JobC{LOCb + (size_t)(d - 1) * 2 * M1, w_state,
                LOCb + (size_t)d * 2 * M1, nullptr, KIND_ROUND, d, 0};
  };

  JobsC J{};
  // L1: P2 | LOC1
  J.j[0] = SQ(w_state, w_state, PW + M1);
  J.j[1] = RD(1);
  k_chain<<<dim3(16, 16, 2), 256, 0, stream>>>(J, embed, ids, HID);
  // L2: P3, P4 | LOC2
  J.j[0] = SQ(PW + M1, w_state, PW + 2 * M1);
  J.j[1] = SQ(PW + M1, PW + M1, PW + 3 * M1);
  J.j[2] = RD(2);
  k_chain<<<dim3(16, 16, 3), 256, 0, stream>>>(J, embed, ids, HID);
  // L3: P5..P8 | LOC3
  J.j[0] = SQ(PW + 3 * M1, w_state, PW + 4 * M1);
  J.j[1] = SQ(PW + 3 * M1, PW + M1, PW + 5 * M1);
  J.j[2] = SQ(PW + 3 * M1, PW + 2 * M1, PW + 6 * M1);
  J.j[3] = SQ(PW + 3 * M1, PW + 3 * M1, PW + 7 * M1);
  J.j[4] = RD(3);
  k_chain<<<dim3(16, 16, 5), 256, 0, stream>>>(J, embed, ids, HID);
  // L4..L7: Q0..Q3 | LOC4..LOC7
  for (int d = 4; d <= 7; ++d) {
    int j = d - 4;
    const float* src = (j == 0) ? (PW + 7 * M1) : (Qf + (size_t)(j - 1) * M1);
    J.j[0] = SQ(src, src, Qf + (size_t)j * M1);
    J.j[1] = RD(d);
    k_chain<<<dim3(16, 16, 2), 256, 0, stream>>>(J, embed, ids, HID);
  }
  // E0 = LOC slab 7 (chunk ends, 2-plane contiguous)
  hipMemcpyAsync(E0, LOCb + 14 * M1, 2 * M1 * sizeof(bf16_t),
                 hipMemcpyDeviceToDevice, stream);

  // levels 0..7 (Hillis-Steele over 256 chunks), fused with Q4..Q6 squarings
  bf16_t* inp = E0;
  bf16_t* outp = E1;
  for (int k = 0; k < 8; ++k) {
    JobsC J2{};
    int nz = 0;
    if (k <= 2) {
      const float* src = Qf + (size_t)(k + 3) * M1;
      J2.j[nz++] = SQ(src, src, Qf + (size_t)(k + 4) * M1);
    }
    const float* Bq = (k == 0) ? (PW + 7 * M1) : (Qf + (size_t)(k - 1) * M1);
    J2.j[nz++] = JobC{inp, Bq, outp, inp, KIND_LEVEL, 0, 4 << k};
    k_chain<<<dim3(16, 16, nz), 256, 0, stream>>>(J2, embed, ids, HID);
    bf16_t* t = inp; inp = outp; outp = t;
  }
  // prefix back in E0 (inp)

  // carry-apply: hidden[b][c*8+d] = LOC[d] + E_{c-1} @ (W^{d+1})^T
  JobsC Jc{};
  for (int d = 0; d < 8; ++d)
    Jc.j[d] = JobC{inp, PW + (size_t)d * M1, nullptr,
                   LOCb + (size_t)d * 2 * M1, KIND_CARRY, d, 4};
  k_chain<<<dim3(16, 16, 8), 256, 0, stream>>>(Jc, embed, ids, HID);

  // LM head
  dim3 gl(NPAD / 256, (BB * TT) / 256);
  k_lmhead2<<<gl, 512, 0, stream>>>(HID, LWB, lm_b, out);
}

// Round 10
// 952.253 us; speedup vs baseline: 1.1890x; 1.1890x over previous
//
#include <hip/hip_runtime.h>
#include <hip/hip_bf16.h>
#include <stdint.h>

#define DD 1024   // hidden dim
#define BB 4      // batch
#define TT 2048   // seq len
#define VV 16000  // vocab
#define LCH 8     // chunk length
#define NR 1024   // BB*(TT/LCH) rows, r = c*4 + b
#define PADR 512  // zero pad rows before E buffers
#define NPAD 16128
#define M1C ((size_t)DD * DD)

typedef __bf16 bf16_t;
typedef float f32x4_t __attribute__((ext_vector_type(4)));
typedef bf16_t bf16x8_t __attribute__((ext_vector_type(8)));
typedef bf16_t bf16x4_t __attribute__((ext_vector_type(4)));

#define KIND_SQ 0
#define KIND_ROUND 1
#define KIND_LEVEL 2
#define KIND_CARRY 3

__device__ __forceinline__ void gload16(const void* g, void* l) {
  __builtin_amdgcn_global_load_lds((const __attribute__((address_space(1))) void*)g,
                                   (__attribute__((address_space(3))) void*)l, 16, 0, 0);
}

// ---------------- fp32 -> bf16 convert (lm_w) ----------------
__global__ __launch_bounds__(256) void k_cvt(const float* __restrict__ src,
                                             bf16_t* __restrict__ dst, int n4) {
  int i = blockIdx.x * blockDim.x + threadIdx.x;
  int stride = gridDim.x * blockDim.x;
  for (; i < n4; i += stride) {
    float4 v = ((const float4*)src)[i];
    union { ushort4 u; bf16_t h[4]; } p;
    p.h[0] = (bf16_t)v.x; p.h[1] = (bf16_t)v.y;
    p.h[2] = (bf16_t)v.z; p.h[3] = (bf16_t)v.w;
    ((ushort4*)dst)[i] = p.u;
  }
}

// ---------------- chain: fp32-in/out split-bf16 MFMA GEMMs -------------------
struct JobF {
  const float* A; const float* B; float* C; const float* Cin;
  int kind; int dlt;
};
struct JobsF { JobF j[8]; };

__global__ __launch_bounds__(256) void k_gatherF(const float* __restrict__ embed,
                                                 const int* __restrict__ ids,
                                                 float* __restrict__ slab0) {
  int r = blockIdx.x;
  int b = r & 3, c = r >> 2;
  int id = ids[b * TT + c * LCH];
  const float4* s = (const float4*)(embed + (size_t)id * DD);
  float4* d = (float4*)(slab0 + (size_t)r * DD);
  for (int i = threadIdx.x; i < DD / 4; i += blockDim.x) d[i] = s[i];
}

template <int NS>
__device__ __forceinline__ void swrite(char* base, int byteoff, float4 v) {
  float r0 = v.x, r1 = v.y, r2 = v.z, r3 = v.w;
#pragma unroll
  for (int p = 0; p < NS; ++p) {
    bf16x4_t h;
    h[0] = (bf16_t)r0; h[1] = (bf16_t)r1; h[2] = (bf16_t)r2; h[3] = (bf16_t)r3;
    *(bf16x4_t*)(base + p * 5120 + byteoff) = h;
    if (p + 1 < NS) {
      r0 -= (float)h[0]; r1 -= (float)h[1]; r2 -= (float)h[2]; r3 -= (float)h[3];
    }
  }
}

// Round-10: double-buffered LDS (one barrier/tile; swrite of tile t+1 overlaps
// frag-reads+MFMA of tile t). Numerics identical to the round-5 kernel.
template <int NS, bool NN, int MODE>  // MODE: 0 plain,1 round,2 level,3 carry
__device__ __forceinline__ void mbodyF(bf16_t* __restrict__ SBall, const JobF& jb,
                                       const float* __restrict__ embed,
                                       const int* __restrict__ ids,
                                       bf16_t* __restrict__ hidden) {
  const float* A = jb.A;
  const float* Bm = jb.B;
  const int tid = threadIdx.x, lane = tid & 63, wave = tid >> 6;
  const int i0 = blockIdx.y * 64, j0 = blockIdx.x * 64;
  const int wm = (wave >> 1) * 32, wn = (wave & 1) * 32;
  char* base0 = (char*)SBall;
  char* base1 = base0 + NS * 2 * 5120;
  const int arow = tid >> 2;
  const int akb = (tid & 3) * 8;
  const int bj = tid & 63, bk4 = (tid >> 6) * 4;
  const int frow = lane & 15, fkb = (lane >> 4) * 16;
  f32x4_t acc[2][2] = {};

  const float* Aptr = A + (size_t)(i0 + arow) * DD + (tid & 3) * 4;
  const float* BptrNT = Bm + (size_t)(j0 + arow) * DD + (tid & 3) * 4;
  const float* BptrNN = Bm + (size_t)bk4 * DD + j0 + bj;

  struct Regs { float4 a0, a1, b0, b1; float s0[4], s1[4]; };

  auto gload = [&](Regs& R, int k0) {
    R.a0 = *(const float4*)(Aptr + k0);
    R.a1 = *(const float4*)(Aptr + k0 + 16);
    if (!NN) {
      R.b0 = *(const float4*)(BptrNT + k0);
      R.b1 = *(const float4*)(BptrNT + k0 + 16);
    } else {
#pragma unroll
      for (int s = 0; s < 4; ++s) R.s0[s] = BptrNN[(size_t)(k0 + s) * DD];
#pragma unroll
      for (int s = 0; s < 4; ++s) R.s1[s] = BptrNN[(size_t)(k0 + 16 + s) * DD];
    }
  };
  auto stage = [&](Regs& R, char* buf) {
    char* Ap = buf;
    char* Bp = buf + NS * 5120;
    swrite<NS>(Ap, arow * 80 + akb, R.a0);
    swrite<NS>(Ap, arow * 80 + akb + 32, R.a1);
    if (!NN) {
      swrite<NS>(Bp, arow * 80 + akb, R.b0);
      swrite<NS>(Bp, arow * 80 + akb + 32, R.b1);
    } else {
      float4 t0; t0.x = R.s0[0]; t0.y = R.s0[1]; t0.z = R.s0[2]; t0.w = R.s0[3];
      float4 t1; t1.x = R.s1[0]; t1.y = R.s1[1]; t1.z = R.s1[2]; t1.w = R.s1[3];
      swrite<NS>(Bp, bj * 80 + bk4 * 2, t0);
      swrite<NS>(Bp, bj * 80 + bk4 * 2 + 32, t1);
    }
  };
  auto compute = [&](char* buf) {
    char* Ap = buf;
    char* Bp = buf + NS * 5120;
    bf16x8_t af[NS][2], bfx[NS][2];
#pragma unroll
    for (int p = 0; p < NS; ++p)
#pragma unroll
      for (int mf = 0; mf < 2; ++mf) {
        af[p][mf] = *(const bf16x8_t*)(Ap + p * 5120 + (wm + mf * 16 + frow) * 80 + fkb);
        bfx[p][mf] = *(const bf16x8_t*)(Bp + p * 5120 + (wn + mf * 16 + frow) * 80 + fkb);
      }
#pragma unroll
    for (int pa = 0; pa < NS; ++pa)
#pragma unroll
      for (int pb = 0; pb < NS; ++pb) {
        if (pa + pb < NS) {
#pragma unroll
          for (int mf = 0; mf < 2; ++mf)
#pragma unroll
            for (int nf = 0; nf < 2; ++nf)
              acc[mf][nf] = __builtin_amdgcn_mfma_f32_16x16x32_bf16(
                  af[pa][mf], bfx[pb][nf], acc[mf][nf], 0, 0, 0);
        }
      }
  };

  Regs R0, R1;
  gload(R0, 0);
  gload(R1, 32);
  stage(R0, base0);
  __syncthreads();
  for (int kt = 0; kt < 32; kt += 2) {
    // tile kt (even): compute buf0; stage tile kt+1 -> buf1; prefetch kt+2 -> R0
    stage(R1, base1);
    if (kt + 2 < 32) gload(R0, (kt + 2) * 32);
    compute(base0);
    __syncthreads();
    // tile kt+1 (odd): compute buf1; stage tile kt+2 -> buf0; prefetch kt+3 -> R1
    if (kt + 2 < 32) stage(R0, base0);
    if (kt + 3 < 32) gload(R1, (kt + 3) * 32);
    compute(base1);
    __syncthreads();
  }

  const int ecol = lane & 15, er4 = (lane >> 4) * 4;
#pragma unroll
  for (int mf = 0; mf < 2; ++mf) {
#pragma unroll
    for (int nf = 0; nf < 2; ++nf) {
      const int rb = i0 + wm + mf * 16 + er4;
      const int cj = j0 + wn + nf * 16 + ecol;
#pragma unroll
      for (int rg = 0; rg < 4; ++rg) {
        const int ri = rb + rg;
        float v = acc[mf][nf][rg];
        if (MODE == 0) {
          jb.C[(size_t)ri * DD + cj] = v;
        } else if (MODE == 1) {
          int b = ri & 3, c = ri >> 2, t = c * LCH + jb.dlt;
          v += embed[(size_t)ids[b * TT + t] * DD + cj];
          jb.C[(size_t)ri * DD + cj] = v;
        } else if (MODE == 2) {
          v += jb.Cin[(size_t)ri * DD + cj];
          jb.C[(size_t)ri * DD + cj] = v;
        } else {
          int b = ri & 3, c = ri >> 2, t = c * LCH + jb.dlt;
          hidden[((size_t)b * TT + t) * DD + cj] =
              (bf16_t)(v + jb.Cin[(size_t)ri * DD + cj]);
        }
      }
    }
  }
}

__global__ __launch_bounds__(256, 2) void k_multiF(JobsF jobs,
                                                   const float* __restrict__ embed,
                                                   const int* __restrict__ ids,
                                                   bf16_t* __restrict__ hidden) {
  __shared__ __align__(16) bf16_t SBb[2 * 6 * 2560];  // 61440 B (2 bufs)
  const JobF& jb = jobs.j[blockIdx.z];
  if (jb.kind == KIND_SQ)
    mbodyF<3, true, 0>(SBb, jb, embed, ids, hidden);
  else if (jb.kind == KIND_ROUND)
    mbodyF<2, false, 1>(SBb, jb, embed, ids, hidden);
  else if (jb.kind == KIND_LEVEL)
    mbodyF<2, false, 2>(SBb, jb, embed, ids, hidden);
  else
    mbodyF<2, false, 3>(SBb, jb, embed, ids, hidden);
}

// ---------------- LM head: round-5 verified kernel (330 us) ------------------
#define NTK 32

__global__ __launch_bounds__(512, 2) void k_lmhead2(
    const bf16_t* __restrict__ Ah, const bf16_t* __restrict__ Bw,
    const float* __restrict__ bias, float* __restrict__ Cout) {
  __shared__ __align__(16) char LB[4 * 32768];
  const int tid = threadIdx.x, lane = tid & 63, wave = tid >> 6;
  const int wr = wave >> 2, wc = wave & 3;
  int orig = blockIdx.y * gridDim.x + blockIdx.x;
  int swz = (orig & 7) * 252 + (orig >> 3);
  int by = swz / 63, bx = swz % 63;
  const int m0 = by * 256, n0 = bx * 256;

  const int srow = tid >> 2;
  const int scb = (tid & 3) * 16;

  auto stage = [&](int t) {
    char* buf = LB + (size_t)(t & 3) * 32768;
#pragma unroll
    for (int p = 0; p < 2; ++p) {
      int row = p * 128 + srow;
      int sw = ((row >> 1) & 3) << 4;
      gload16((const char*)Ah + ((size_t)(m0 + row) * DD + t * 32) * 2 + (scb ^ sw),
              buf + p * 8192 + wave * 1024);
      gload16((const char*)Bw + ((size_t)(n0 + row) * DD + t * 32) * 2 + (scb ^ sw),
              buf + 16384 + p * 8192 + wave * 1024);
    }
  };

  const int frow = lane & 15;
  const int c4b = (lane >> 4) * 16;
  f32x4_t acc[8][4] = {};

  stage(0); stage(1); stage(2);
  asm volatile("s_waitcnt vmcnt(8)\ns_barrier" ::: "memory");

  for (int t = 0; t < NTK; ++t) {
    char* Abuf = LB + (size_t)(t & 3) * 32768;
    char* Bbuf = Abuf + 16384;
    if (t + 3 < NTK) stage(t + 3);
    bf16x8_t afr[4], bfr[4];
#pragma unroll
    for (int nf = 0; nf < 4; ++nf) {
      int r = wc * 64 + nf * 16 + frow;
      bfr[nf] = *(const bf16x8_t*)(Bbuf + r * 64 + (c4b ^ (((r >> 1) & 3) << 4)));
    }
#pragma unroll
    for (int mf = 0; mf < 4; ++mf) {
      int r = wr * 128 + mf * 16 + frow;
      afr[mf] = *(const bf16x8_t*)(Abuf + r * 64 + (c4b ^ (((r >> 1) & 3) << 4)));
    }
    __builtin_amdgcn_s_setprio(1);
#pragma unroll
    for (int mf = 0; mf < 4; ++mf)
#pragma unroll
      for (int nf = 0; nf < 4; ++nf)
        acc[mf][nf] = __builtin_amdgcn_mfma_f32_16x16x32_bf16(
            afr[mf], bfr[nf], acc[mf][nf], 0, 0, 0);
    __builtin_amdgcn_s_setprio(0);
#pragma unroll
    for (int mf = 0; mf < 4; ++mf) {
      int r = wr * 128 + 64 + mf * 16 + frow;
      afr[mf] = *(const bf16x8_t*)(Abuf + r * 64 + (c4b ^ (((r >> 1) & 3) << 4)));
    }
    __builtin_amdgcn_s_setprio(1);
#pragma unroll
    for (int mf = 0; mf < 4; ++mf)
#pragma unroll
      for (int nf = 0; nf < 4; ++nf)
        acc[4 + mf][nf] = __builtin_amdgcn_mfma_f32_16x16x32_bf16(
            afr[mf], bfr[nf], acc[4 + mf][nf], 0, 0, 0);
    __builtin_amdgcn_s_setprio(0);
    if (t < NTK - 3) {
      asm volatile("s_waitcnt vmcnt(8)\ns_barrier" ::: "memory");
    } else if (t == NTK - 3) {
      asm volatile("s_waitcnt vmcnt(4)\ns_barrier" ::: "memory");
    } else if (t == NTK - 2) {
      asm volatile("s_waitcnt vmcnt(0)\ns_barrier" ::: "memory");
    }
  }

  const int ecol = lane & 15, er4 = (lane >> 4) * 4;
#pragma unroll
  for (int mf = 0; mf < 8; ++mf) {
#pragma unroll
    for (int nf = 0; nf < 4; ++nf) {
      int gm = m0 + wr * 128 + mf * 16 + er4;
      int gn = n0 + wc * 64 + nf * 16 + ecol;
      if (gn < VV) {
        float bv = bias[gn];
#pragma unroll
        for (int rg = 0; rg < 4; ++rg)
          Cout[(size_t)(gm + rg) * VV + gn] = acc[mf][nf][rg] + bv;
      }
    }
  }
}

// ---------------- host orchestration (round-5 verified schedule) -------------
extern "C" void kernel_launch(void* const* d_in, const int* in_sizes, int n_in,
                              void* d_out, int out_size, void* d_ws, size_t ws_size,
                              hipStream_t stream) {
  (void)in_sizes; (void)n_in; (void)out_size; (void)ws_size;
  const int* ids = (const int*)d_in[0];
  const float* embed = (const float*)d_in[1];
  const float* w_state = (const float*)d_in[2];
  const float* lm_w = (const float*)d_in[3];
  const float* lm_b = (const float*)d_in[4];
  float* out = (float*)d_out;

  const size_t M1 = M1C;
  float* PW = (float*)d_ws;                 // 8*M1 : PW + n*M1 = W^{n+1}
  float* Q = PW + 8 * M1;                   // 7*M1
  float* LOC = Q + 7 * M1;                  // 8*M1
  float* E0 = LOC + 8 * M1;
  float* E1 = E0 + (size_t)(PADR + NR) * DD;
  bf16_t* HID = (bf16_t*)(E1 + (size_t)(PADR + NR) * DD);
  bf16_t* LWB = HID + (size_t)BB * TT * DD;
  float* E0d = E0 + (size_t)PADR * DD;
  float* E1d = E1 + (size_t)PADR * DD;

  k_cvt<<<2048, 256, 0, stream>>>(lm_w, LWB, VV * DD / 4);
  hipMemsetAsync(LWB + (size_t)VV * DD, 0,
                 (size_t)(NPAD - VV) * DD * sizeof(bf16_t), stream);
  hipMemcpyAsync(PW, w_state, M1 * sizeof(float), hipMemcpyDeviceToDevice, stream);
  k_gatherF<<<NR, 256, 0, stream>>>(embed, ids, LOC);
  hipMemsetAsync(E0, 0, (size_t)PADR * DD * sizeof(float), stream);
  hipMemsetAsync(E1, 0, (size_t)PADR * DD * sizeof(float), stream);

  JobsF J{};
  J.j[0] = JobF{w_state, w_state, PW + M1, nullptr, KIND_SQ, 0};
  J.j[1] = JobF{LOC, w_state, LOC + M1, nullptr, KIND_ROUND, 1};
  k_multiF<<<dim3(16, 16, 2), 256, 0, stream>>>(J, embed, ids, HID);
  J.j[0] = JobF{PW + M1, w_state, PW + 2 * M1, nullptr, KIND_SQ, 0};
  J.j[1] = JobF{PW + M1, PW + M1, PW + 3 * M1, nullptr, KIND_SQ, 0};
  J.j[2] = JobF{LOC + M1, w_state, LOC + 2 * M1, nullptr, KIND_ROUND, 2};
  k_multiF<<<dim3(16, 16, 3), 256, 0, stream>>>(J, embed, ids, HID);
  J.j[0] = JobF{PW + 3 * M1, w_state, PW + 4 * M1, nullptr, KIND_SQ, 0};
  J.j[1] = JobF{PW + 3 * M1, PW + M1, PW + 5 * M1, nullptr, KIND_SQ, 0};
  J.j[2] = JobF{PW + 3 * M1, PW + 2 * M1, PW + 6 * M1, nullptr, KIND_SQ, 0};
  J.j[3] = JobF{PW + 3 * M1, PW + 3 * M1, PW + 7 * M1, nullptr, KIND_SQ, 0};
  J.j[4] = JobF{LOC + 2 * M1, w_state, LOC + 3 * M1, nullptr, KIND_ROUND, 3};
  k_multiF<<<dim3(16, 16, 5), 256, 0, stream>>>(J, embed, ids, HID);
  for (int d = 4; d <= 7; ++d) {
    const float* src = (d == 4) ? (PW + 7 * M1) : (Q + (size_t)(d - 5) * M1);
    J.j[0] = JobF{src, src, Q + (size_t)(d - 4) * M1, nullptr, KIND_SQ, 0};
    J.j[1] = JobF{LOC + (size_t)(d - 1) * M1, w_state, LOC + (size_t)d * M1,
                  nullptr, KIND_ROUND, d};
    k_multiF<<<dim3(16, 16, 2), 256, 0, stream>>>(J, embed, ids, HID);
  }
  hipMemcpyAsync(E0d, LOC + 7 * M1, M1 * sizeof(float),
                 hipMemcpyDeviceToDevice, stream);

  float* inp = E0d;
  float* outp = E1d;
  for (int k = 0; k < 8; ++k) {
    JobsF J2{};
    int nz = 0;
    if (k <= 2) {
      const float* src = Q + (size_t)(k + 3) * M1;
      J2.j[nz++] = JobF{src, src, Q + (size_t)(k + 4) * M1, nullptr, KIND_SQ, 0};
    }
    const float* Bq = (k == 0) ? (PW + 7 * M1) : (Q + (size_t)(k - 1) * M1);
    J2.j[nz++] = JobF{inp - (size_t)(4 << k) * DD, Bq, outp, inp, KIND_LEVEL, 0};
    k_multiF<<<dim3(16, 16, nz), 256, 0, stream>>>(J2, embed, ids, HID);
    float* t = inp; inp = outp; outp = t;
  }

  JobsF Jc{};
  for (int d = 0; d < 8; ++d)
    Jc.j[d] = JobF{inp - (size_t)4 * DD, PW + (size_t)d * M1, nullptr,
                   LOC + (size_t)d * M1, KIND_CARRY, d};
  k_multiF<<<dim3(16, 16, 8), 256, 0, stream>>>(Jc, embed, ids, HID);

  dim3 gl(NPAD / 256, (BB * TT) / 256);
  k_lmhead2<<<gl, 512, 0, stream>>>(HID, LWB, lm_b, out);
}